// Round 28
// baseline (88.478 us; speedup 1.0000x reference)
//
#include <hip/hip_runtime.h>

typedef _Float16 f16x8 __attribute__((ext_vector_type(8)));
typedef __fp16 hf2 __attribute__((ext_vector_type(2)));
typedef float f32x4 __attribute__((ext_vector_type(4)));

#define MFMA32(A, B, C) __builtin_amdgcn_mfma_f32_16x16x32_f16(A, B, C, 0, 0, 0)
#define NEG_LOG2E (-1.4426950408889634f)
#define PRIO1() __builtin_amdgcn_s_setprio(1)
#define PRIO0() __builtin_amdgcn_s_setprio(0)

extern "C" __device__ float __ocml_native_exp2_f32(float);  // v_exp_f32: 2^x

struct P16 { f16x8 hi, lo; };

__device__ __forceinline__ f16x8 pk8(const float* v) {
  uint4 u;
  u.x = __builtin_bit_cast(unsigned, __builtin_amdgcn_cvt_pkrtz(v[0], v[1]));
  u.y = __builtin_bit_cast(unsigned, __builtin_amdgcn_cvt_pkrtz(v[2], v[3]));
  u.z = __builtin_bit_cast(unsigned, __builtin_amdgcn_cvt_pkrtz(v[4], v[5]));
  u.w = __builtin_bit_cast(unsigned, __builtin_amdgcn_cvt_pkrtz(v[6], v[7]));
  return __builtin_bit_cast(f16x8, u);
}
__device__ __forceinline__ P16 splitpk(const float* v) {
  unsigned uh[4], ul[4];
  float lo[8];
#pragma unroll
  for (int e = 0; e < 4; ++e) {
    const hf2 h = __builtin_amdgcn_cvt_pkrtz(v[2 * e], v[2 * e + 1]);
    uh[e] = __builtin_bit_cast(unsigned, h);
    lo[2 * e]     = v[2 * e]     - (float)h[0];
    lo[2 * e + 1] = v[2 * e + 1] - (float)h[1];
  }
#pragma unroll
  for (int e = 0; e < 4; ++e)
    ul[e] = __builtin_bit_cast(unsigned, __builtin_amdgcn_cvt_pkrtz(lo[2 * e], lo[2 * e + 1]));
  P16 p;
  p.hi = __builtin_bit_cast(f16x8, uint4{uh[0], uh[1], uh[2], uh[3]});
  p.lo = __builtin_bit_cast(f16x8, uint4{ul[0], ul[1], ul[2], ul[3]});
  return p;
}
__device__ __forceinline__ P16 splitpk16(float4 a, float4 b) {
  float v[8] = {a.x, a.y, a.z, a.w, b.x, b.y, b.z, b.w};
  return splitpk(v);
}
__device__ __forceinline__ float sigm2(float a) {
  return __builtin_amdgcn_rcpf(1.0f + __ocml_native_exp2_f32(a));
}

// prep: W' = -log2e * W -> f16 hi/lo fragment planes; scaled bias fragments.
__global__ void prep_wfrag(const float* __restrict__ W, const float* __restrict__ bias,
                           uint4* __restrict__ wf, f32x4* __restrict__ bf) {
  const int id = blockIdx.x * 256 + threadIdx.x;
  if (id < 2048) {
    const int T = id >> 6, l = id & 63, g = (l >> 4) & 3, li = l & 15;
    const int col = 16 * T + li;
    unsigned hi[8], lo[8];
#pragma unroll
    for (int e = 0; e < 8; ++e) {
      const int k = (e < 4) ? (4 * g + e) : (16 + 4 * g + (e - 4));
      const float v = (k < 28) ? W[col * 28 + k] * NEG_LOG2E : 0.0f;
      const _Float16 h = (_Float16)v;
      const _Float16 lw = (_Float16)(v - (float)h);
      hi[e] = __builtin_bit_cast(unsigned short, h);
      lo[e] = __builtin_bit_cast(unsigned short, lw);
    }
    uint4 uh, ul;
    uh.x = hi[0] | (hi[1] << 16); uh.y = hi[2] | (hi[3] << 16);
    uh.z = hi[4] | (hi[5] << 16); uh.w = hi[6] | (hi[7] << 16);
    ul.x = lo[0] | (lo[1] << 16); ul.y = lo[2] | (lo[3] << 16);
    ul.z = lo[4] | (lo[5] << 16); ul.w = lo[6] | (lo[7] << 16);
    wf[T * 64 + l] = uh;
    wf[(32 + T) * 64 + l] = ul;
  }
  if (id < 1024) {
    const int s = id >> 6, l = id & 63, g = (l >> 4) & 3;
    f32x4 b0, b1;
#pragma unroll
    for (int e = 0; e < 4; ++e) {
      b0[e] = bias[32 * s + 4 * g + e] * NEG_LOG2E;
      b1[e] = bias[32 * s + 16 + 4 * g + e] * NEG_LOG2E;
    }
    bf[id * 2 + 0] = b0;
    bf[id * 2 + 1] = b1;
  }
}

// ONE WAVE = ONE SAMPLE (R27 base, 87.6us). R28: TRUE depth-2 W prefetch in
// both hot loops via explicitly doubled bodies with two register sets (no
// moves, no runtime-indexed arrays). Load-use distance = 2 full bodies,
// covering L2 latency under 16-wave/CU contention. R24's depth-2 test was
// confounded by the libm-exp2f regression; this is the untested cell.
__global__ __launch_bounds__(256, 4) void elm_kernel(
    const float* __restrict__ x, const uint4* __restrict__ wf,
    const f32x4* __restrict__ bf, const float* __restrict__ bias,
    float* __restrict__ Xout, float* __restrict__ Bout)
{
  __shared__ __align__(16) float sm[4096];   // 4 x 1024-word wave regions
  const int tid = threadIdx.x;
  const int w = tid >> 6, l = tid & 63, gl = l >> 4, li = l & 15;
  const int n = blockIdx.x * 4 + w;
  const int wb = w * 1024;
  const float* xi = x + (size_t)n * 784;

  // ---- 1. x fragments ----
  const float4 z4 = {0, 0, 0, 0};
  const float4 xa0 = *reinterpret_cast<const float4*>(xi + li * 28 + 4 * gl);
  const float4 xb0 = (gl < 3) ? *reinterpret_cast<const float4*>(xi + li * 28 + 16 + 4 * gl) : z4;
  const int r1 = (li < 12) ? 16 + li : 0;
  float4 xa1 = *reinterpret_cast<const float4*>(xi + r1 * 28 + 4 * gl);
  float4 xb1 = (gl < 3) ? *reinterpret_cast<const float4*>(xi + r1 * 28 + 16 + 4 * gl) : z4;
  if (li >= 12) { xa1 = z4; xb1 = z4; }
  const P16 X0 = splitpk16(xa0, xb0);
  const P16 X1 = splitpk16(xa1, xb1);

  // ---- 2. G phase: 16 chunks, wave-staggered, depth-2 W pipeline ----
  f32x4 d00 = {0, 0, 0, 0}, d01 = {0, 0, 0, 0}, d11 = {0, 0, 0, 0};
  const int c0 = 4 * w, c1 = (4 * w + 1) & 15;
  uint4 A0h = wf[(2 * c0) * 64 + l],     A0l = wf[(32 + 2 * c0) * 64 + l];
  uint4 A1h = wf[(2 * c0 + 1) * 64 + l], A1l = wf[(32 + 2 * c0 + 1) * 64 + l];
  uint4 B0h = wf[(2 * c1) * 64 + l],     B0l = wf[(32 + 2 * c1) * 64 + l];
  uint4 B1h = wf[(2 * c1 + 1) * 64 + l], B1l = wf[(32 + 2 * c1 + 1) * 64 + l];
#pragma unroll 1
  for (int ss = 0; ss < 16; ss += 2) {
    // ---- body A: chunk ss, set A, reload A for ss+2 ----
    {
      const int s  = (ss + 4 * w) & 15;
      const int s2 = (ss + 2 + 4 * w) & 15;
      const f16x8 W0h = __builtin_bit_cast(f16x8, A0h);
      const f16x8 W0l = __builtin_bit_cast(f16x8, A0l);
      const f16x8 W1h = __builtin_bit_cast(f16x8, A1h);
      const f16x8 W1l = __builtin_bit_cast(f16x8, A1l);
      f32x4 P0 = bf[(s * 64 + l) * 2 + 0];
      f32x4 Q0 = bf[(s * 64 + l) * 2 + 1];
      f32x4 P1 = P0, Q1 = Q0;
      PRIO1();
      P0 = MFMA32(W0h, X0.hi, P0); P0 = MFMA32(W0h, X0.lo, P0); P0 = MFMA32(W0l, X0.hi, P0);
      Q0 = MFMA32(W1h, X0.hi, Q0); Q0 = MFMA32(W1h, X0.lo, Q0); Q0 = MFMA32(W1l, X0.hi, Q0);
      P1 = MFMA32(W0h, X1.hi, P1); P1 = MFMA32(W0h, X1.lo, P1); P1 = MFMA32(W0l, X1.hi, P1);
      Q1 = MFMA32(W1h, X1.hi, Q1); Q1 = MFMA32(W1h, X1.lo, Q1); Q1 = MFMA32(W1l, X1.hi, Q1);
      PRIO0();
      A0h = wf[(2 * s2) * 64 + l];          // reload set A for ss+2
      A0l = wf[(32 + 2 * s2) * 64 + l];
      A1h = wf[(2 * s2 + 1) * 64 + l];
      A1l = wf[(32 + 2 * s2 + 1) * 64 + l];
      float f0[8], f1[8];
#pragma unroll
      for (int i = 0; i < 4; ++i) {
        f0[i] = sigm2(P0[i]); f0[4 + i] = sigm2(Q0[i]);
        f1[i] = sigm2(P1[i]); f1[4 + i] = sigm2(Q1[i]);
      }
      const P16 F0 = splitpk(f0);
      const P16 F1 = splitpk(f1);
      PRIO1();
      d00 = MFMA32(F0.hi, F0.hi, d00); d00 = MFMA32(F0.hi, F0.lo, d00); d00 = MFMA32(F0.lo, F0.hi, d00);
      d01 = MFMA32(F0.hi, F1.hi, d01); d01 = MFMA32(F0.hi, F1.lo, d01); d01 = MFMA32(F0.lo, F1.hi, d01);
      d11 = MFMA32(F1.hi, F1.hi, d11); d11 = MFMA32(F1.hi, F1.lo, d11); d11 = MFMA32(F1.lo, F1.hi, d11);
      PRIO0();
    }
    // ---- body B: chunk ss+1, set B, reload B for ss+3 ----
    {
      const int s  = (ss + 1 + 4 * w) & 15;
      const int s2 = (ss + 3 + 4 * w) & 15;
      const f16x8 W0h = __builtin_bit_cast(f16x8, B0h);
      const f16x8 W0l = __builtin_bit_cast(f16x8, B0l);
      const f16x8 W1h = __builtin_bit_cast(f16x8, B1h);
      const f16x8 W1l = __builtin_bit_cast(f16x8, B1l);
      f32x4 P0 = bf[(s * 64 + l) * 2 + 0];
      f32x4 Q0 = bf[(s * 64 + l) * 2 + 1];
      f32x4 P1 = P0, Q1 = Q0;
      PRIO1();
      P0 = MFMA32(W0h, X0.hi, P0); P0 = MFMA32(W0h, X0.lo, P0); P0 = MFMA32(W0l, X0.hi, P0);
      Q0 = MFMA32(W1h, X0.hi, Q0); Q0 = MFMA32(W1h, X0.lo, Q0); Q0 = MFMA32(W1l, X0.hi, Q0);
      P1 = MFMA32(W0h, X1.hi, P1); P1 = MFMA32(W0h, X1.lo, P1); P1 = MFMA32(W0l, X1.hi, P1);
      Q1 = MFMA32(W1h, X1.hi, Q1); Q1 = MFMA32(W1h, X1.lo, Q1); Q1 = MFMA32(W1l, X1.hi, Q1);
      PRIO0();
      B0h = wf[(2 * s2) * 64 + l];          // reload set B for ss+3
      B0l = wf[(32 + 2 * s2) * 64 + l];
      B1h = wf[(2 * s2 + 1) * 64 + l];
      B1l = wf[(32 + 2 * s2 + 1) * 64 + l];
      float f0[8], f1[8];
#pragma unroll
      for (int i = 0; i < 4; ++i) {
        f0[i] = sigm2(P0[i]); f0[4 + i] = sigm2(Q0[i]);
        f1[i] = sigm2(P1[i]); f1[4 + i] = sigm2(Q1[i]);
      }
      const P16 F0 = splitpk(f0);
      const P16 F1 = splitpk(f1);
      PRIO1();
      d00 = MFMA32(F0.hi, F0.hi, d00); d00 = MFMA32(F0.hi, F0.lo, d00); d00 = MFMA32(F0.lo, F0.hi, d00);
      d01 = MFMA32(F0.hi, F1.hi, d01); d01 = MFMA32(F0.hi, F1.lo, d01); d01 = MFMA32(F0.lo, F1.hi, d01);
      d11 = MFMA32(F1.hi, F1.hi, d11); d11 = MFMA32(F1.hi, F1.lo, d11); d11 = MFMA32(F1.lo, F1.hi, d11);
      PRIO0();
    }
  }

  // ---- 3. G fragments -> per-wave LDS Gc[r*32+c] (d01 mirrored = d10) ----
#pragma unroll
  for (int i = 0; i < 4; ++i) {
    const int ra = 4 * gl + i;
    sm[wb + ra * 32 + li] = d00[i];
    sm[wb + ra * 32 + 16 + li] = d01[i];
    sm[wb + (16 + li) * 32 + ra] = d01[i];
    sm[wb + (16 + ra) * 32 + 16 + li] = d11[i];
  }

  // ---- 4. X = x copy (overlaps solve) + B-phase depth-2 preload ----
  {
    const float4* x4 = reinterpret_cast<const float4*>(xi);
    float4* X4 = reinterpret_cast<float4*>(Xout + (size_t)n * 784);
#pragma unroll
    for (int k = 0; k < 4; ++k) {
      const int idx = l + 64 * k;
      if (idx < 196) X4[idx] = x4[idx];
    }
  }
  const int T0 = (8 * w) & 31, T1 = (8 * w + 1) & 31;
  uint4 qh = wf[T0 * 64 + l], ql = wf[(32 + T0) * 64 + l];
  uint4 rh = wf[T1 * 64 + l], rl = wf[(32 + T1) * 64 + l];
  float qb = bias[16 * T0 + li], rb = bias[16 * T1 + li];

  // ---- 5. solve G Y = x : per-wave Gauss-Jordan; RHS from global x ----
  {
    const int j = l;
    float col[28];
#pragma unroll
    for (int r = 0; r < 28; ++r) {
      float v = 0.f;
      if (j < 28)      v = sm[wb + r * 32 + j];
      else if (j < 56) v = xi[r * 28 + (j - 28)];
      col[r] = v;
    }
#pragma unroll
    for (int k = 0; k < 28; ++k) {
      const float piv = __shfl(col[k], k);
      const float pivinv = 1.0f / piv;
      col[k] *= pivinv;
#pragma unroll
      for (int r2 = 0; r2 < 28; ++r2) {
        if (r2 == k) continue;
        const float m = __shfl(col[r2], k);
        col[r2] -= m * col[k];
      }
    }
    if (j >= 28 && j < 56) {          // Y^T: sm[c*32 + r]; zero col-pads
      const int c = j - 28;
#pragma unroll
      for (int r2 = 0; r2 < 28; ++r2) sm[wb + c * 32 + r2] = col[r2];
      *reinterpret_cast<float4*>(&sm[wb + c * 32 + 28]) = z4;
    }
    if (j >= 56) {                    // zero pad rows 28..31 (2 lanes/row)
      const int rr = 28 + ((j - 56) >> 1), half = (j - 56) & 1;
#pragma unroll
      for (int t = 0; t < 4; ++t)
        *reinterpret_cast<float4*>(&sm[wb + rr * 32 + half * 16 + 4 * t]) = z4;
    }
  }

  // ---- 6. Y A-fragments from per-wave Yt ----
  const P16 Y0 = splitpk16(*reinterpret_cast<const float4*>(&sm[wb + li * 32 + 4 * gl]),
                           *reinterpret_cast<const float4*>(&sm[wb + li * 32 + 16 + 4 * gl]));
  const P16 Y1 = splitpk16(*reinterpret_cast<const float4*>(&sm[wb + (16 + li) * 32 + 4 * gl]),
                           *reinterpret_cast<const float4*>(&sm[wb + (16 + li) * 32 + 16 + 4 * gl]));

  // ---- 7. B = H~^T Y : 2-term H, depth-2 W+bias pipeline, staggered ----
  float* Bo = Bout + (size_t)n * 14336;
#pragma unroll 1
  for (int t = 0; t < 32; t += 2) {
    // ---- body A: tile t, set q, reload q for t+2 ----
    {
      const int T  = (t + 8 * w) & 31;
      const int T2 = (t + 2 + 8 * w) & 31;
      const f16x8 Whi = __builtin_bit_cast(f16x8, qh);
      const f16x8 Wlo = __builtin_bit_cast(f16x8, ql);
      const float bv = qb * NEG_LOG2E;
      f32x4 a0 = {bv, bv, bv, bv}, a1 = {bv, bv, bv, bv};
      PRIO1();
      a0 = MFMA32(X0.hi, Whi, a0); a0 = MFMA32(X0.hi, Wlo, a0);
      a1 = MFMA32(X1.hi, Whi, a1); a1 = MFMA32(X1.hi, Wlo, a1);
      PRIO0();
      qh = wf[T2 * 64 + l]; ql = wf[(32 + T2) * 64 + l]; qb = bias[16 * T2 + li];
      float hv[8];
#pragma unroll
      for (int i = 0; i < 4; ++i) { hv[i] = sigm2(a0[i]); hv[4 + i] = sigm2(a1[i]); }
      const f16x8 Bhi = pk8(hv);
      f32x4 bt0 = {0, 0, 0, 0}, bt1 = {0, 0, 0, 0};
      PRIO1();
      bt0 = MFMA32(Y0.hi, Bhi, bt0); bt0 = MFMA32(Y0.lo, Bhi, bt0);
      bt1 = MFMA32(Y1.hi, Bhi, bt1); bt1 = MFMA32(Y1.lo, Bhi, bt1);
      PRIO0();
      float* Brow = Bo + (16 * T + li) * 28;
      *reinterpret_cast<float4*>(Brow + 4 * gl) = float4{bt0[0], bt0[1], bt0[2], bt0[3]};
      if (gl < 3)
        *reinterpret_cast<float4*>(Brow + 16 + 4 * gl) = float4{bt1[0], bt1[1], bt1[2], bt1[3]};
    }
    // ---- body B: tile t+1, set r, reload r for t+3 ----
    {
      const int T  = (t + 1 + 8 * w) & 31;
      const int T2 = (t + 3 + 8 * w) & 31;
      const f16x8 Whi = __builtin_bit_cast(f16x8, rh);
      const f16x8 Wlo = __builtin_bit_cast(f16x8, rl);
      const float bv = rb * NEG_LOG2E;
      f32x4 a0 = {bv, bv, bv, bv}, a1 = {bv, bv, bv, bv};
      PRIO1();
      a0 = MFMA32(X0.hi, Whi, a0); a0 = MFMA32(X0.hi, Wlo, a0);
      a1 = MFMA32(X1.hi, Whi, a1); a1 = MFMA32(X1.hi, Wlo, a1);
      PRIO0();
      rh = wf[T2 * 64 + l]; rl = wf[(32 + T2) * 64 + l]; rb = bias[16 * T2 + li];
      float hv[8];
#pragma unroll
      for (int i = 0; i < 4; ++i) { hv[i] = sigm2(a0[i]); hv[4 + i] = sigm2(a1[i]); }
      const f16x8 Bhi = pk8(hv);
      f32x4 bt0 = {0, 0, 0, 0}, bt1 = {0, 0, 0, 0};
      PRIO1();
      bt0 = MFMA32(Y0.hi, Bhi, bt0); bt0 = MFMA32(Y0.lo, Bhi, bt0);
      bt1 = MFMA32(Y1.hi, Bhi, bt1); bt1 = MFMA32(Y1.lo, Bhi, bt1);
      PRIO0();
      float* Brow = Bo + (16 * T + li) * 28;
      *reinterpret_cast<float4*>(Brow + 4 * gl) = float4{bt0[0], bt0[1], bt0[2], bt0[3]};
      if (gl < 3)
        *reinterpret_cast<float4*>(Brow + 16 + 4 * gl) = float4{bt1[0], bt1[1], bt1[2], bt1[3]};
    }
  }
}

extern "C" void kernel_launch(void* const* d_in, const int* in_sizes, int n_in,
                              void* d_out, int out_size, void* d_ws, size_t ws_size,
                              hipStream_t stream) {
  const float* x = (const float*)d_in[0];
  const float* W = (const float*)d_in[1];
  const float* b = (const float*)d_in[2];
  const int N = in_sizes[0] / 784;               // 4096 samples
  float* Xout = (float*)d_out;                   // [N,1,28,28]
  float* Bout = Xout + (size_t)N * 784;          // [N,1,512,28]
  uint4* wf = (uint4*)d_ws;                      // 65536 B
  f32x4* bfr = (f32x4*)((char*)d_ws + 65536);    // 32768 B
  prep_wfrag<<<8, 256, 0, stream>>>(W, b, wf, bfr);
  elm_kernel<<<N / 4, 256, 0, stream>>>(x, wf, bfr, b, Xout, Bout);
}

// Round 29
// 87.895 us; speedup vs baseline: 1.0066x; 1.0066x over previous
//
#include <hip/hip_runtime.h>

typedef _Float16 f16x8 __attribute__((ext_vector_type(8)));
typedef __fp16 hf2 __attribute__((ext_vector_type(2)));
typedef float f32x4 __attribute__((ext_vector_type(4)));

#define MFMA32(A, B, C) __builtin_amdgcn_mfma_f32_16x16x32_f16(A, B, C, 0, 0, 0)
#define NEG_LOG2E (-1.4426950408889634f)
#define PRIO1() __builtin_amdgcn_s_setprio(1)
#define PRIO0() __builtin_amdgcn_s_setprio(0)

extern "C" __device__ float __ocml_native_exp2_f32(float);  // v_exp_f32: 2^x

struct P16 { f16x8 hi, lo; };

// packed-pair f32->f16 conversion (1 op / 2 elems, pre-packed)
__device__ __forceinline__ f16x8 pk8(const float* v) {
  uint4 u;
  u.x = __builtin_bit_cast(unsigned, __builtin_amdgcn_cvt_pkrtz(v[0], v[1]));
  u.y = __builtin_bit_cast(unsigned, __builtin_amdgcn_cvt_pkrtz(v[2], v[3]));
  u.z = __builtin_bit_cast(unsigned, __builtin_amdgcn_cvt_pkrtz(v[4], v[5]));
  u.w = __builtin_bit_cast(unsigned, __builtin_amdgcn_cvt_pkrtz(v[6], v[7]));
  return __builtin_bit_cast(f16x8, u);
}
// hi/lo split via pkrtz: hi=RTZ(v), lo=RTZ(v-hi) (residual exact, 3-term ~2^-22)
__device__ __forceinline__ P16 splitpk(const float* v) {
  unsigned uh[4], ul[4];
  float lo[8];
#pragma unroll
  for (int e = 0; e < 4; ++e) {
    const hf2 h = __builtin_amdgcn_cvt_pkrtz(v[2 * e], v[2 * e + 1]);
    uh[e] = __builtin_bit_cast(unsigned, h);
    lo[2 * e]     = v[2 * e]     - (float)h[0];
    lo[2 * e + 1] = v[2 * e + 1] - (float)h[1];
  }
#pragma unroll
  for (int e = 0; e < 4; ++e)
    ul[e] = __builtin_bit_cast(unsigned, __builtin_amdgcn_cvt_pkrtz(lo[2 * e], lo[2 * e + 1]));
  P16 p;
  p.hi = __builtin_bit_cast(f16x8, uint4{uh[0], uh[1], uh[2], uh[3]});
  p.lo = __builtin_bit_cast(f16x8, uint4{ul[0], ul[1], ul[2], ul[3]});
  return p;
}
__device__ __forceinline__ P16 splitpk16(float4 a, float4 b) {
  float v[8] = {a.x, a.y, a.z, a.w, b.x, b.y, b.z, b.w};
  return splitpk(v);
}
// input already pre-scaled by -log2(e): h = 1/(1 + 2^a), native v_exp path
__device__ __forceinline__ float sigm2(float a) {
  return __builtin_amdgcn_rcpf(1.0f + __ocml_native_exp2_f32(a));
}

// prep: W' = -log2e * W [512][28] -> f16 hi/lo fragment planes wf[{0,1}*32+T][lane];
// element e: k = 4g+e (e<4) | 16+4g+(e-4), g=lane>>4; W-col = 16T + (lane&15).
// ALSO scaled bias fragments bf[(s*64+l)*2 + {0,1}] = -log2e * bias.
__global__ void prep_wfrag(const float* __restrict__ W, const float* __restrict__ bias,
                           uint4* __restrict__ wf, f32x4* __restrict__ bf) {
  const int id = blockIdx.x * 256 + threadIdx.x;
  if (id < 2048) {
    const int T = id >> 6, l = id & 63, g = (l >> 4) & 3, li = l & 15;
    const int col = 16 * T + li;
    unsigned hi[8], lo[8];
#pragma unroll
    for (int e = 0; e < 8; ++e) {
      const int k = (e < 4) ? (4 * g + e) : (16 + 4 * g + (e - 4));
      const float v = (k < 28) ? W[col * 28 + k] * NEG_LOG2E : 0.0f;
      const _Float16 h = (_Float16)v;
      const _Float16 lw = (_Float16)(v - (float)h);
      hi[e] = __builtin_bit_cast(unsigned short, h);
      lo[e] = __builtin_bit_cast(unsigned short, lw);
    }
    uint4 uh, ul;
    uh.x = hi[0] | (hi[1] << 16); uh.y = hi[2] | (hi[3] << 16);
    uh.z = hi[4] | (hi[5] << 16); uh.w = hi[6] | (hi[7] << 16);
    ul.x = lo[0] | (lo[1] << 16); ul.y = lo[2] | (lo[3] << 16);
    ul.z = lo[4] | (lo[5] << 16); ul.w = lo[6] | (lo[7] << 16);
    wf[T * 64 + l] = uh;
    wf[(32 + T) * 64 + l] = ul;
  }
  if (id < 1024) {
    const int s = id >> 6, l = id & 63, g = (l >> 4) & 3;
    f32x4 b0, b1;
#pragma unroll
    for (int e = 0; e < 4; ++e) {
      b0[e] = bias[32 * s + 4 * g + e] * NEG_LOG2E;
      b1[e] = bias[32 * s + 16 + 4 * g + e] * NEG_LOG2E;
    }
    bf[id * 2 + 0] = b0;
    bf[id * 2 + 1] = b1;
  }
}

// ONE WAVE = ONE SAMPLE — final form (R27, 87.6us best measured).
// H~ via swapped-operand MFMA (out-fragment == G/B operand fragment, no LDS
// transpose); G = H~H~^T 3-term f16 split, symmetric (d00/d01/d11);
// per-wave Gauss-Jordan solve; X = x (H full row-rank); B = H~^T Y with
// 2-term H recompute. pkrtz splits, -log2e folded into wf/bf, bias as MFMA
// C-init, depth-1 W prefetch, wave-staggered orders, setprio on MFMA bursts.
// ZERO barriers; direct B stores.
__global__ __launch_bounds__(256, 4) void elm_kernel(
    const float* __restrict__ x, const uint4* __restrict__ wf,
    const f32x4* __restrict__ bf, const float* __restrict__ bias,
    float* __restrict__ Xout, float* __restrict__ Bout)
{
  __shared__ __align__(16) float sm[4096];   // 4 x 1024-word wave regions
  const int tid = threadIdx.x;
  const int w = tid >> 6, l = tid & 63, gl = l >> 4, li = l & 15;
  const int n = blockIdx.x * 4 + w;
  const int wb = w * 1024;
  const float* xi = x + (size_t)n * 784;

  // ---- 1. x fragments (lane = x-row li / 16+li, elems = x-cols) ----
  const float4 z4 = {0, 0, 0, 0};
  const float4 xa0 = *reinterpret_cast<const float4*>(xi + li * 28 + 4 * gl);
  const float4 xb0 = (gl < 3) ? *reinterpret_cast<const float4*>(xi + li * 28 + 16 + 4 * gl) : z4;
  const int r1 = (li < 12) ? 16 + li : 0;
  float4 xa1 = *reinterpret_cast<const float4*>(xi + r1 * 28 + 4 * gl);
  float4 xb1 = (gl < 3) ? *reinterpret_cast<const float4*>(xi + r1 * 28 + 16 + 4 * gl) : z4;
  if (li >= 12) { xa1 = z4; xb1 = z4; }
  const P16 X0 = splitpk16(xa0, xb0);
  const P16 X1 = splitpk16(xa1, xb1);

  // ---- 2. G phase: 16 chunks of 32 h, wave-staggered, W prefetch depth 1,
  //         scaled bias pre-loaded into the MFMA C-operand ----
  f32x4 d00 = {0, 0, 0, 0}, d01 = {0, 0, 0, 0}, d11 = {0, 0, 0, 0};
  const int s_first = 4 * w;                    // (0 + 4w) & 15
  uint4 pW0h = wf[(2 * s_first) * 64 + l];
  uint4 pW0l = wf[(32 + 2 * s_first) * 64 + l];
  uint4 pW1h = wf[(2 * s_first + 1) * 64 + l];
  uint4 pW1l = wf[(32 + 2 * s_first + 1) * 64 + l];
#pragma unroll 2
  for (int ss = 0; ss < 16; ++ss) {
    const int s = (ss + 4 * w) & 15;            // wave-staggered chunk order
    const int sn = (ss + 1 + 4 * w) & 15;       // next chunk (last wraps, harmless)
    const f16x8 W0h = __builtin_bit_cast(f16x8, pW0h);
    const f16x8 W0l = __builtin_bit_cast(f16x8, pW0l);
    const f16x8 W1h = __builtin_bit_cast(f16x8, pW1h);
    const f16x8 W1l = __builtin_bit_cast(f16x8, pW1l);
    pW0h = wf[(2 * sn) * 64 + l];               // prefetch next chunk's W
    pW0l = wf[(32 + 2 * sn) * 64 + l];
    pW1h = wf[(2 * sn + 1) * 64 + l];
    pW1l = wf[(32 + 2 * sn + 1) * 64 + l];
    f32x4 P0 = bf[(s * 64 + l) * 2 + 0];        // scaled bias as C-init
    f32x4 Q0 = bf[(s * 64 + l) * 2 + 1];
    f32x4 P1 = P0, Q1 = Q0;
    PRIO1();
    P0 = MFMA32(W0h, X0.hi, P0); P0 = MFMA32(W0h, X0.lo, P0); P0 = MFMA32(W0l, X0.hi, P0);
    Q0 = MFMA32(W1h, X0.hi, Q0); Q0 = MFMA32(W1h, X0.lo, Q0); Q0 = MFMA32(W1l, X0.hi, Q0);
    P1 = MFMA32(W0h, X1.hi, P1); P1 = MFMA32(W0h, X1.lo, P1); P1 = MFMA32(W0l, X1.hi, P1);
    Q1 = MFMA32(W1h, X1.hi, Q1); Q1 = MFMA32(W1h, X1.lo, Q1); Q1 = MFMA32(W1l, X1.hi, Q1);
    PRIO0();
    float f0[8], f1[8];
#pragma unroll
    for (int i = 0; i < 4; ++i) {
      f0[i]     = sigm2(P0[i]);
      f0[4 + i] = sigm2(Q0[i]);
      f1[i]     = sigm2(P1[i]);
      f1[4 + i] = sigm2(Q1[i]);
    }
    const P16 F0 = splitpk(f0);
    const P16 F1 = splitpk(f1);
    PRIO1();
    d00 = MFMA32(F0.hi, F0.hi, d00); d00 = MFMA32(F0.hi, F0.lo, d00); d00 = MFMA32(F0.lo, F0.hi, d00);
    d01 = MFMA32(F0.hi, F1.hi, d01); d01 = MFMA32(F0.hi, F1.lo, d01); d01 = MFMA32(F0.lo, F1.hi, d01);
    d11 = MFMA32(F1.hi, F1.hi, d11); d11 = MFMA32(F1.hi, F1.lo, d11); d11 = MFMA32(F1.lo, F1.hi, d11);
    PRIO0();
  }

  // ---- 3. G fragments -> per-wave LDS Gc[r*32+c] (d01 mirrored = d10) ----
#pragma unroll
  for (int i = 0; i < 4; ++i) {
    const int ra = 4 * gl + i;
    sm[wb + ra * 32 + li] = d00[i];
    sm[wb + ra * 32 + 16 + li] = d01[i];
    sm[wb + (16 + li) * 32 + ra] = d01[i];
    sm[wb + (16 + ra) * 32 + 16 + li] = d11[i];
  }

  // ---- 4. X = x copy (stores overlap the solve) + B-phase prefetch ----
  {
    const float4* x4 = reinterpret_cast<const float4*>(xi);
    float4* X4 = reinterpret_cast<float4*>(Xout + (size_t)n * 784);
#pragma unroll
    for (int k = 0; k < 4; ++k) {
      const int idx = l + 64 * k;
      if (idx < 196) X4[idx] = x4[idx];
    }
  }
  uint4 pWh = wf[((8 * w) & 31) * 64 + l];      // B-phase prefetch: hidden by solve
  uint4 pWl = wf[(32 + ((8 * w) & 31)) * 64 + l];
  float pbv = bias[16 * ((8 * w) & 31) + li];

  // ---- 5. solve G Y = x : per-wave Gauss-Jordan; RHS from global x ----
  {
    const int j = l;
    float col[28];
#pragma unroll
    for (int r = 0; r < 28; ++r) {
      float v = 0.f;
      if (j < 28)      v = sm[wb + r * 32 + j];
      else if (j < 56) v = xi[r * 28 + (j - 28)];
      col[r] = v;
    }
#pragma unroll
    for (int k = 0; k < 28; ++k) {
      const float piv = __shfl(col[k], k);
      const float pivinv = 1.0f / piv;
      col[k] *= pivinv;
#pragma unroll
      for (int r2 = 0; r2 < 28; ++r2) {
        if (r2 == k) continue;
        const float m = __shfl(col[r2], k);
        col[r2] -= m * col[k];
      }
    }
    if (j >= 28 && j < 56) {          // Y^T: sm[c*32 + r]; zero col-pads
      const int c = j - 28;
#pragma unroll
      for (int r2 = 0; r2 < 28; ++r2) sm[wb + c * 32 + r2] = col[r2];
      *reinterpret_cast<float4*>(&sm[wb + c * 32 + 28]) = z4;
    }
    if (j >= 56) {                    // zero pad rows 28..31 (2 lanes/row)
      const int rr = 28 + ((j - 56) >> 1), half = (j - 56) & 1;
#pragma unroll
      for (int t = 0; t < 4; ++t)
        *reinterpret_cast<float4*>(&sm[wb + rr * 32 + half * 16 + 4 * t]) = z4;
    }
  }

  // ---- 6. Y A-fragments from per-wave Yt ----
  const P16 Y0 = splitpk16(*reinterpret_cast<const float4*>(&sm[wb + li * 32 + 4 * gl]),
                           *reinterpret_cast<const float4*>(&sm[wb + li * 32 + 16 + 4 * gl]));
  const P16 Y1 = splitpk16(*reinterpret_cast<const float4*>(&sm[wb + (16 + li) * 32 + 4 * gl]),
                           *reinterpret_cast<const float4*>(&sm[wb + (16 + li) * 32 + 16 + 4 * gl]));

  // ---- 7. B = H~^T Y : 2-term H recompute, depth-1 W+bias prefetch, staggered;
  //         scaled bias as C-init; no pad guards (Y zero at k>=28) ----
  float* Bo = Bout + (size_t)n * 14336;
#pragma unroll 2
  for (int t = 0; t < 32; ++t) {
    const int T = (t + 8 * w) & 31;             // wave-staggered tile order
    const int Tn = (t + 1 + 8 * w) & 31;        // next tile (wraps once, harmless)
    const f16x8 Whi = __builtin_bit_cast(f16x8, pWh);
    const f16x8 Wlo = __builtin_bit_cast(f16x8, pWl);
    const float bv = pbv * NEG_LOG2E;
    pWh = wf[Tn * 64 + l];                      // prefetch next tile's W + bias
    pWl = wf[(32 + Tn) * 64 + l];
    pbv = bias[16 * Tn + li];
    f32x4 a0 = {bv, bv, bv, bv}, a1 = {bv, bv, bv, bv};
    PRIO1();
    a0 = MFMA32(X0.hi, Whi, a0); a0 = MFMA32(X0.hi, Wlo, a0);   // 2-term
    a1 = MFMA32(X1.hi, Whi, a1); a1 = MFMA32(X1.hi, Wlo, a1);
    PRIO0();
    float hv[8];
#pragma unroll
    for (int i = 0; i < 4; ++i) {
      hv[i]     = sigm2(a0[i]);
      hv[4 + i] = sigm2(a1[i]);     // r>=28 garbage is multiplied by Y==0
    }
    const f16x8 Bhi = pk8(hv);
    f32x4 bt0 = {0, 0, 0, 0}, bt1 = {0, 0, 0, 0};
    PRIO1();
    bt0 = MFMA32(Y0.hi, Bhi, bt0); bt0 = MFMA32(Y0.lo, Bhi, bt0);
    bt1 = MFMA32(Y1.hi, Bhi, bt1); bt1 = MFMA32(Y1.lo, Bhi, bt1);
    PRIO0();
    float* Brow = Bo + (16 * T + li) * 28;
    *reinterpret_cast<float4*>(Brow + 4 * gl) = float4{bt0[0], bt0[1], bt0[2], bt0[3]};
    if (gl < 3)
      *reinterpret_cast<float4*>(Brow + 16 + 4 * gl) = float4{bt1[0], bt1[1], bt1[2], bt1[3]};
  }
}

extern "C" void kernel_launch(void* const* d_in, const int* in_sizes, int n_in,
                              void* d_out, int out_size, void* d_ws, size_t ws_size,
                              hipStream_t stream) {
  const float* x = (const float*)d_in[0];
  const float* W = (const float*)d_in[1];
  const float* b = (const float*)d_in[2];
  const int N = in_sizes[0] / 784;               // 4096 samples
  float* Xout = (float*)d_out;                   // [N,1,28,28]
  float* Bout = Xout + (size_t)N * 784;          // [N,1,512,28]
  uint4* wf = (uint4*)d_ws;                      // 65536 B
  f32x4* bfr = (f32x4*)((char*)d_ws + 65536);    // 32768 B
  prep_wfrag<<<8, 256, 0, stream>>>(W, b, wf, bfr);
  elm_kernel<<<N / 4, 256, 0, stream>>>(x, wf, bfr, b, Xout, Bout);
}